// Round 4
// baseline (120.187 us; speedup 1.0000x reference)
//
#include <hip/hip_runtime.h>
#include <stdint.h>

// BitNetLinear eval forward on MI355X (gfx950).
// M = B*S = 32768, K = 1024 (in_features), N = 1024 (out_features).
//
// R3: GEMM keeps 256x256/BK=64/8-wave but B-frags come DIRECTLY from global
// (qw is 1MB, L2-resident) via pinned inline-asm loads one K-tile ahead;
// LDS carries A only (double-buffered 2x16KB, depth-1 prefetch, counted
// vmcnt(4)/vmcnt(6)). Removes 1/3 of LDS reads + 1/2 of staging -> MFMA-bound.
// Also: kmax+ksum fused (kprep); kfin folded into kquant_w / kquant_x.

#define MK_M 32768
#define MK_K 1024
#define MK_N 1024

typedef __attribute__((ext_vector_type(4))) int int32x4;

// ---- workspace layout ----
// [0]    float w_scale      [4] float i_scale
// [64]   float maxp[2048]   (per-block |x| maxima, rewritten every call)
// [8448] double partials[64](|W| partial sums, rewritten every call)
// [16384]        qw (1 MB)
// [16384 + 1 MB] qx (32 MB)
#define WS_MAXP_OFF 64
#define WS_PART_OFF 8448
#define WS_QW_OFF 16384
#define WS_QX_OFF (16384 + (1 << 20))
#define WS_NEEDED (WS_QX_OFF + (size_t)MK_M * MK_K)

// fused: blocks [0,2048) -> per-block max|x|; blocks [2048,2112) -> partial sum|W|
__global__ void kprep(const float4* __restrict__ x4, const float4* __restrict__ w4,
                      float* __restrict__ maxp, double* __restrict__ partials, long n4x) {
    const int bid = blockIdx.x;
    if (bid < 2048) {
        float m = 0.f;
        const long stride = 2048L * 256;
        for (long i = (long)bid * 256 + threadIdx.x; i < n4x; i += stride) {
            float4 v = x4[i];
            m = fmaxf(m, fmaxf(fmaxf(fabsf(v.x), fabsf(v.y)), fmaxf(fabsf(v.z), fabsf(v.w))));
        }
        #pragma unroll
        for (int off = 1; off < 64; off <<= 1) m = fmaxf(m, __shfl_xor(m, off));
        __shared__ float sm[4];
        int lane = threadIdx.x & 63, wid = threadIdx.x >> 6;
        if (lane == 0) sm[wid] = m;
        __syncthreads();
        if (threadIdx.x == 0) maxp[bid] = fmaxf(fmaxf(sm[0], sm[1]), fmaxf(sm[2], sm[3]));
    } else {
        double s = 0.0;
        for (int i = (bid - 2048) * 256 + threadIdx.x; i < (1 << 18); i += 64 * 256) {
            float4 v = w4[i];
            s += (double)fabsf(v.x);
            s += (double)fabsf(v.y);
            s += (double)fabsf(v.z);
            s += (double)fabsf(v.w);
        }
        __shared__ double sd[256];
        sd[threadIdx.x] = s;
        __syncthreads();
        for (int h = 128; h > 0; h >>= 1) {
            if ((int)threadIdx.x < h) sd[threadIdx.x] += sd[threadIdx.x + h];
            __syncthreads();
        }
        if (threadIdx.x == 0) partials[bid - 2048] = sd[0];
    }
}

// every block redundantly reduces partials[64] in the SAME fixed order
// (butterfly over wave 0) -> identical deterministic w_scale everywhere.
__global__ void kquant_w(const float4* __restrict__ w4, unsigned* __restrict__ qw,
                         const double* __restrict__ partials, float* __restrict__ wscp) {
    __shared__ double sws;
    if (threadIdx.x < 64) {
        double s = partials[threadIdx.x];
        #pragma unroll
        for (int off = 1; off < 64; off <<= 1) s += __shfl_xor(s, off);
        if (threadIdx.x == 0) sws = s;
    }
    __syncthreads();
    float wsc = (float)(sws / 1048576.0);   // mean|W| over 2^20 elements
    if (blockIdx.x == 0 && threadIdx.x == 0) *wscp = wsc;
    float thr = 0.5f * wsc;
    int stride = gridDim.x * blockDim.x;
    for (int i = blockIdx.x * blockDim.x + threadIdx.x; i < (1 << 18); i += stride) {
        float4 v = w4[i];
        int q0 = (fabsf(v.x) > thr) ? (v.x > 0.f ? 1 : -1) : 0;
        int q1 = (fabsf(v.y) > thr) ? (v.y > 0.f ? 1 : -1) : 0;
        int q2 = (fabsf(v.z) > thr) ? (v.z > 0.f ? 1 : -1) : 0;
        int q3 = (fabsf(v.w) > thr) ? (v.w > 0.f ? 1 : -1) : 0;
        qw[i] = (q0 & 0xff) | ((q1 & 0xff) << 8) | ((q2 & 0xff) << 16) | ((q3 & 0xff) << 24);
    }
}

// every block redundantly reduces maxp[2048] (max is order-independent).
__global__ void kquant_x(const float4* __restrict__ x4, unsigned* __restrict__ qx,
                         const float* __restrict__ maxp, float* __restrict__ iscp, long n4) {
    float m = 0.f;
    #pragma unroll
    for (int j = 0; j < 8; ++j) m = fmaxf(m, maxp[threadIdx.x + 256 * j]);
    #pragma unroll
    for (int off = 1; off < 64; off <<= 1) m = fmaxf(m, __shfl_xor(m, off));
    __shared__ float sm[4];
    int lane = threadIdx.x & 63, wid = threadIdx.x >> 6;
    if (lane == 0) sm[wid] = m;
    __syncthreads();
    float isc = fmaxf(fmaxf(sm[0], sm[1]), fmaxf(sm[2], sm[3])) / 127.0f;  // fp32 div, matches ref
    if (blockIdx.x == 0 && threadIdx.x == 0) *iscp = isc;
    long stride = (long)gridDim.x * blockDim.x;
    for (long i = (long)blockIdx.x * blockDim.x + threadIdx.x; i < n4; i += stride) {
        float4 v = x4[i];
        // IEEE divide + rint (half-to-even) to match jnp.round(x / i_scale)
        float q0 = fminf(fmaxf(rintf(v.x / isc), -128.f), 127.f);
        float q1 = fminf(fmaxf(rintf(v.y / isc), -128.f), 127.f);
        float q2 = fminf(fmaxf(rintf(v.z / isc), -128.f), 127.f);
        float q3 = fminf(fmaxf(rintf(v.w / isc), -128.f), 127.f);
        int i0 = (int)q0, i1 = (int)q1, i2 = (int)q2, i3 = (int)q3;
        qx[i] = (i0 & 0xff) | ((i1 & 0xff) << 8) | ((i2 & 0xff) << 16) | ((i3 & 0xff) << 24);
    }
}

// ---- int8 GEMM: out[m][n] = sum_k qx[m][k] * qw[n][k] ----
// 256x256 tile, BK=64, 8 waves (2Mx4N), per-wave 128x64 out (acc 8x4 frags).
// A: LDS double-buffer (2x16KB), staged via global_load_lds (2/thread/K-tile),
//    XOR chunk swizzle (ch ^= (row>>1)&3) pre-applied on the GLOBAL source.
// B: pinned asm global_load_dwordx4 straight from qw (L2-resident), one
//    K-tile ahead into the alternate bfA/bfB set (even/odd bodies).
// Waits (derived, see R3 notes): top vmcnt(4) -> stage(kt) done, bf(kt) in
// flight; pre-MFMA vmcnt(6) lgkmcnt(0) -> bf(kt)+ds_reads done, stage(kt+1)
// + bf(kt+1) stay in flight. Never drains mid-loop.
__global__ __launch_bounds__(512, 2) void kgemm(
    const char* __restrict__ qx, const char* __restrict__ qw,
    const float* __restrict__ bias, const float* __restrict__ wscp,
    const float* __restrict__ iscp, float* __restrict__ out)
{
    __shared__ __align__(16) char smem[2 * 16384];

    const int t = threadIdx.x;
    const int l = t & 63;
    const int w = t >> 6;          // 0..7
    const int wm = w >> 2;         // 0..1  (M half)
    const int wn = w & 3;          // 0..3  (N quarter)

    // XCD-bijective swizzle: 512 blocks, 8 XCDs, 64 contiguous per XCD.
    const int bid = blockIdx.x;
    const int wg = (bid & 7) * 64 + (bid >> 3);
    const int tm = wg >> 2, tn = wg & 3;
    const long m0 = (long)tm * 256;
    const int n0 = tn * 256;

    // A staging: K-tile = 256 rows x 64B = 16KB = 512 thr x 32B (2 units).
    // thread t covers row (t>>2) of each 128-row unit, chunk t&3 (pre-swizzled).
    const int grow = t >> 2;
    const int gch = (t & 3) ^ ((grow >> 1) & 3);
    const char* gAt = qx + (m0 + grow) * (long)MK_K + gch * 16;

    auto stage = [&](int kt1, int b) {
        char* dst = smem + b * 16384 + t * 16;
        const char* src = gAt + kt1 * 64;
        __builtin_amdgcn_global_load_lds(
            (const __attribute__((address_space(1))) void*)src,
            (__attribute__((address_space(3))) void*)dst, 16, 0, 0);
        __builtin_amdgcn_global_load_lds(
            (const __attribute__((address_space(1))) void*)(src + 128 * (long)MK_K),
            (__attribute__((address_space(3))) void*)(dst + 8192), 16, 0, 0);
    };

    // B lane voffsets (constant across K-tiles); saddr walks kt*64.
    const unsigned vo0 = (unsigned)((n0 + wn * 64 + 0 * 16 + (l & 15)) * MK_K + (l >> 4) * 16);
    const unsigned vo1 = vo0 + 16 * MK_K;
    const unsigned vo2 = vo0 + 32 * MK_K;
    const unsigned vo3 = vo0 + 48 * MK_K;

    int32x4 acc[8][4];
    #pragma unroll
    for (int mi = 0; mi < 8; ++mi)
        #pragma unroll
        for (int ni = 0; ni < 4; ++ni) acc[mi][ni] = (int32x4)0;

    int32x4 bfA[4], bfB[4];

    // prologue: stage K-tile 0 into buf 0; load bfA(0). Queue: stage0[2], bfA0[4].
    stage(0, 0);
    {
        const char* sb = qw;
        asm volatile("global_load_dwordx4 %0, %1, %2" : "=v"(bfA[0]) : "v"(vo0), "s"(sb));
        asm volatile("global_load_dwordx4 %0, %1, %2" : "=v"(bfA[1]) : "v"(vo1), "s"(sb));
        asm volatile("global_load_dwordx4 %0, %1, %2" : "=v"(bfA[2]) : "v"(vo2), "s"(sb));
        asm volatile("global_load_dwordx4 %0, %1, %2" : "=v"(bfA[3]) : "v"(vo3), "s"(sb));
    }

    auto body = [&](int kt, int32x4 (&bfc)[4], int32x4 (&bfn)[4]) {
        // stage(kt) done (drain to 4: bf(kt) stays in flight)
        asm volatile("s_waitcnt vmcnt(4)" ::: "memory");
        __builtin_amdgcn_s_barrier();
        __builtin_amdgcn_sched_barrier(0);

        const char* bufA = smem + (kt & 1) * 16384;
        int32x4 af[8];
        #pragma unroll
        for (int i = 0; i < 8; ++i) {
            int row = wm * 128 + i * 16 + (l & 15);
            int ch = (l >> 4) ^ ((row >> 1) & 3);
            af[i] = *(const int32x4*)(bufA + row * 64 + ch * 16);
        }
        if (kt < 15) {
            stage(kt + 1, (kt + 1) & 1);
            const char* sb = qw + (kt + 1) * 64;
            asm volatile("global_load_dwordx4 %0, %1, %2" : "=v"(bfn[0]) : "v"(vo0), "s"(sb));
            asm volatile("global_load_dwordx4 %0, %1, %2" : "=v"(bfn[1]) : "v"(vo1), "s"(sb));
            asm volatile("global_load_dwordx4 %0, %1, %2" : "=v"(bfn[2]) : "v"(vo2), "s"(sb));
            asm volatile("global_load_dwordx4 %0, %1, %2" : "=v"(bfn[3]) : "v"(vo3), "s"(sb));
            // bf(kt) done; stage(kt+1)[2] + bf(kt+1)[4] remain in flight
            asm volatile("s_waitcnt vmcnt(6) lgkmcnt(0)" ::: "memory");
        } else {
            asm volatile("s_waitcnt vmcnt(0) lgkmcnt(0)" ::: "memory");
        }
        __builtin_amdgcn_sched_barrier(0);
        __builtin_amdgcn_s_setprio(1);
        #pragma unroll
        for (int mi = 0; mi < 8; ++mi)
            #pragma unroll
            for (int ni = 0; ni < 4; ++ni)
                acc[mi][ni] = __builtin_amdgcn_mfma_i32_16x16x64_i8(
                    af[mi], bfc[ni], acc[mi][ni], 0, 0, 0);
        __builtin_amdgcn_s_setprio(0);
    };

    for (int kb = 0; kb < 8; ++kb) {
        body(2 * kb,     bfA, bfB);
        body(2 * kb + 1, bfB, bfA);
    }

    // epilogue: C/D layout col = lane&15, row = (lane>>4)*4 + reg (verified)
    const float wsc = *wscp, isc = *iscp;
    const int crow = (l >> 4) * 4;
    const int ccol = l & 15;
    #pragma unroll
    for (int mi = 0; mi < 8; ++mi) {
        #pragma unroll
        for (int ni = 0; ni < 4; ++ni) {
            long r0 = m0 + wm * 128 + mi * 16 + crow;
            int c = n0 + wn * 64 + ni * 16 + ccol;
            float b = bias[c];
            #pragma unroll
            for (int j = 0; j < 4; ++j) {
                out[(r0 + j) * MK_N + c] = ((float)acc[mi][ni][j] * wsc) * isc + b;
            }
        }
    }
}

extern "C" void kernel_launch(void* const* d_in, const int* in_sizes, int n_in,
                              void* d_out, int out_size, void* d_ws, size_t ws_size,
                              hipStream_t stream) {
    const float* x = (const float*)d_in[0];
    const float* wt = (const float*)d_in[1];
    const float* bias = (const float*)d_in[2];
    float* out = (float*)d_out;

    if (ws_size < WS_NEEDED) return;

    char* ws = (char*)d_ws;
    float* wscp = (float*)(ws + 0);
    float* iscp = (float*)(ws + 4);
    float* maxp = (float*)(ws + WS_MAXP_OFF);
    double* partials = (double*)(ws + WS_PART_OFF);
    char* qw = ws + WS_QW_OFF;
    char* qx = ws + WS_QX_OFF;

    const long n_x = (long)in_sizes[0];   // 33554432
    const long n4_x = n_x >> 2;

    kprep<<<2112, 256, 0, stream>>>((const float4*)x, (const float4*)wt, maxp, partials, n4_x);
    kquant_w<<<256, 256, 0, stream>>>((const float4*)wt, (unsigned*)qw, partials, wscp);
    kquant_x<<<2048, 256, 0, stream>>>((const float4*)x, (unsigned*)qx, maxp, iscp, n4_x);

    const int grid = (MK_M / 256) * (MK_N / 256);  // 512
    kgemm<<<grid, 512, 0, stream>>>(qx, qw, bias, wscp, iscp, out);
}

// Round 5
// 110.613 us; speedup vs baseline: 1.0866x; 1.0866x over previous
//
#include <hip/hip_runtime.h>
#include <stdint.h>

// BitNetLinear eval forward on MI355X (gfx950).
// M = B*S = 32768, K = 1024 (in_features), N = 1024 (out_features).
//
// R4: GEMM = 128x128 tile, 256 threads (4 waves 2x2), per-wave 64x64
// (acc[4][4] = 64 AGPR -> ~120 unified regs -> 4 waves/SIMD allowed),
// LDS 3x16KB triple-buffer -> 3 independent blocks/CU (barrier decoupling).
// R2's proven wait pattern: stage(kt+2), counted vmcnt(4), compiler lgkm.
// Non-GEMM pipeline unchanged from R3 (kprep fused, kfin folded, ~42us).

#define MK_M 32768
#define MK_K 1024
#define MK_N 1024

typedef __attribute__((ext_vector_type(4))) int int32x4;

// ---- workspace layout ----
// [0]    float w_scale      [4] float i_scale
// [64]   float maxp[2048]   (per-block |x| maxima, rewritten every call)
// [8448] double partials[64](|W| partial sums, rewritten every call)
// [16384]        qw (1 MB)
// [16384 + 1 MB] qx (32 MB)
#define WS_MAXP_OFF 64
#define WS_PART_OFF 8448
#define WS_QW_OFF 16384
#define WS_QX_OFF (16384 + (1 << 20))
#define WS_NEEDED (WS_QX_OFF + (size_t)MK_M * MK_K)

// fused: blocks [0,2048) -> per-block max|x|; blocks [2048,2112) -> partial sum|W|
__global__ void kprep(const float4* __restrict__ x4, const float4* __restrict__ w4,
                      float* __restrict__ maxp, double* __restrict__ partials, long n4x) {
    const int bid = blockIdx.x;
    if (bid < 2048) {
        float m = 0.f;
        const long stride = 2048L * 256;
        for (long i = (long)bid * 256 + threadIdx.x; i < n4x; i += stride) {
            float4 v = x4[i];
            m = fmaxf(m, fmaxf(fmaxf(fabsf(v.x), fabsf(v.y)), fmaxf(fabsf(v.z), fabsf(v.w))));
        }
        #pragma unroll
        for (int off = 1; off < 64; off <<= 1) m = fmaxf(m, __shfl_xor(m, off));
        __shared__ float sm[4];
        int lane = threadIdx.x & 63, wid = threadIdx.x >> 6;
        if (lane == 0) sm[wid] = m;
        __syncthreads();
        if (threadIdx.x == 0) maxp[bid] = fmaxf(fmaxf(sm[0], sm[1]), fmaxf(sm[2], sm[3]));
    } else {
        double s = 0.0;
        for (int i = (bid - 2048) * 256 + threadIdx.x; i < (1 << 18); i += 64 * 256) {
            float4 v = w4[i];
            s += (double)fabsf(v.x);
            s += (double)fabsf(v.y);
            s += (double)fabsf(v.z);
            s += (double)fabsf(v.w);
        }
        __shared__ double sd[256];
        sd[threadIdx.x] = s;
        __syncthreads();
        for (int h = 128; h > 0; h >>= 1) {
            if ((int)threadIdx.x < h) sd[threadIdx.x] += sd[threadIdx.x + h];
            __syncthreads();
        }
        if (threadIdx.x == 0) partials[bid - 2048] = sd[0];
    }
}

// every block redundantly reduces partials[64] in the SAME fixed order
// (butterfly over wave 0) -> identical deterministic w_scale everywhere.
__global__ void kquant_w(const float4* __restrict__ w4, unsigned* __restrict__ qw,
                         const double* __restrict__ partials, float* __restrict__ wscp) {
    __shared__ double sws;
    if (threadIdx.x < 64) {
        double s = partials[threadIdx.x];
        #pragma unroll
        for (int off = 1; off < 64; off <<= 1) s += __shfl_xor(s, off);
        if (threadIdx.x == 0) sws = s;
    }
    __syncthreads();
    float wsc = (float)(sws / 1048576.0);   // mean|W| over 2^20 elements
    if (blockIdx.x == 0 && threadIdx.x == 0) *wscp = wsc;
    float thr = 0.5f * wsc;
    int stride = gridDim.x * blockDim.x;
    for (int i = blockIdx.x * blockDim.x + threadIdx.x; i < (1 << 18); i += stride) {
        float4 v = w4[i];
        int q0 = (fabsf(v.x) > thr) ? (v.x > 0.f ? 1 : -1) : 0;
        int q1 = (fabsf(v.y) > thr) ? (v.y > 0.f ? 1 : -1) : 0;
        int q2 = (fabsf(v.z) > thr) ? (v.z > 0.f ? 1 : -1) : 0;
        int q3 = (fabsf(v.w) > thr) ? (v.w > 0.f ? 1 : -1) : 0;
        qw[i] = (q0 & 0xff) | ((q1 & 0xff) << 8) | ((q2 & 0xff) << 16) | ((q3 & 0xff) << 24);
    }
}

// every block redundantly reduces maxp[2048] (max is order-independent).
__global__ void kquant_x(const float4* __restrict__ x4, unsigned* __restrict__ qx,
                         const float* __restrict__ maxp, float* __restrict__ iscp, long n4) {
    float m = 0.f;
    #pragma unroll
    for (int j = 0; j < 8; ++j) m = fmaxf(m, maxp[threadIdx.x + 256 * j]);
    #pragma unroll
    for (int off = 1; off < 64; off <<= 1) m = fmaxf(m, __shfl_xor(m, off));
    __shared__ float sm[4];
    int lane = threadIdx.x & 63, wid = threadIdx.x >> 6;
    if (lane == 0) sm[wid] = m;
    __syncthreads();
    float isc = fmaxf(fmaxf(sm[0], sm[1]), fmaxf(sm[2], sm[3])) / 127.0f;  // fp32 div, matches ref
    if (blockIdx.x == 0 && threadIdx.x == 0) *iscp = isc;
    long stride = (long)gridDim.x * blockDim.x;
    for (long i = (long)blockIdx.x * blockDim.x + threadIdx.x; i < n4; i += stride) {
        float4 v = x4[i];
        // IEEE divide + rint (half-to-even) to match jnp.round(x / i_scale)
        float q0 = fminf(fmaxf(rintf(v.x / isc), -128.f), 127.f);
        float q1 = fminf(fmaxf(rintf(v.y / isc), -128.f), 127.f);
        float q2 = fminf(fmaxf(rintf(v.z / isc), -128.f), 127.f);
        float q3 = fminf(fmaxf(rintf(v.w / isc), -128.f), 127.f);
        int i0 = (int)q0, i1 = (int)q1, i2 = (int)q2, i3 = (int)q3;
        qx[i] = (i0 & 0xff) | ((i1 & 0xff) << 8) | ((i2 & 0xff) << 16) | ((i3 & 0xff) << 24);
    }
}

// ---- int8 GEMM: out[m][n] = sum_k qx[m][k] * qw[n][k] ----
// 128x128 tile, BK=64, 4 waves (2Mx2N), per-wave 64x64 (acc 4x4 frags).
// Triple-buffered LDS (3 x (A 8KB + B 8KB) = 48KB), stage(kt+2) depth-2
// prefetch, counted vmcnt(4) (T4), compiler-managed lgkm for ds_read->MFMA.
// Swizzle (verified 0-conflict R1/R2): chunk ch of row r stored at
// ch ^ ((r>>1)&3); applied by pre-swizzling the GLOBAL source, LDS linear.
// 3 blocks/CU co-resident -> barrier windows of one block are filled by the
// other blocks' waves (the R2 stall was lockstep-barrier CU idling).
__global__ __launch_bounds__(256, 3) void kgemm(
    const char* __restrict__ qx, const char* __restrict__ qw,
    const float* __restrict__ bias, const float* __restrict__ wscp,
    const float* __restrict__ iscp, float* __restrict__ out)
{
    __shared__ __align__(16) char smem[3 * 16384];

    const int t = threadIdx.x;
    const int l = t & 63;
    const int w = t >> 6;          // 0..3
    const int wm = w >> 1;         // 0..1  (M half)
    const int wn = w & 1;          // 0..1  (N half)

    // XCD-bijective swizzle: 2048 blocks, 8 XCDs, 256 contiguous per XCD;
    // 8 consecutive wg share tm (A panel) -> A reuse within one XCD's L2.
    const int bid = blockIdx.x;
    const int wg = (bid & 7) * 256 + (bid >> 3);
    const int tm = wg >> 3, tn = wg & 7;
    const long m0 = (long)tm * 128;
    const int n0 = tn * 128;

    // staging: K-tile A = 128 rows x 64B = 8KB, two 64-row units; B same.
    // thread t covers rows (t>>2) and (t>>2)+64, chunk t&3 (pre-swizzled;
    // (row>>1)&3 identical for row and row+64 since 32 % 4 == 0).
    const int grow = t >> 2;
    const int gch = (t & 3) ^ ((t >> 3) & 3);
    const char* gAt = qx + (m0 + grow) * (long)MK_K + gch * 16;
    const char* gBt = qw + (long)(n0 + grow) * MK_K + gch * 16;

    auto stage = [&](int kt1, int b) {
        char* dst = smem + b * 16384 + t * 16;
        const char* sa = gAt + kt1 * 64;
        const char* sb = gBt + kt1 * 64;
        __builtin_amdgcn_global_load_lds(
            (const __attribute__((address_space(1))) void*)sa,
            (__attribute__((address_space(3))) void*)dst, 16, 0, 0);
        __builtin_amdgcn_global_load_lds(
            (const __attribute__((address_space(1))) void*)(sa + 64 * (long)MK_K),
            (__attribute__((address_space(3))) void*)(dst + 4096), 16, 0, 0);
        __builtin_amdgcn_global_load_lds(
            (const __attribute__((address_space(1))) void*)sb,
            (__attribute__((address_space(3))) void*)(dst + 8192), 16, 0, 0);
        __builtin_amdgcn_global_load_lds(
            (const __attribute__((address_space(1))) void*)(sb + 64 * (long)MK_K),
            (__attribute__((address_space(3))) void*)(dst + 12288), 16, 0, 0);
    };

    int32x4 acc[4][4];
    #pragma unroll
    for (int mi = 0; mi < 4; ++mi)
        #pragma unroll
        for (int ni = 0; ni < 4; ++ni) acc[mi][ni] = (int32x4)0;

    // prologue: tiles 0,1 into buffers 0,1 (8 loads in flight per wave)
    stage(0, 0);
    stage(1, 1);

    #pragma unroll
    for (int kt = 0; kt < 16; ++kt) {
        // wait for tile kt's 4 units; keep tile kt+1's 4 in flight (T4).
        if (kt < 15) asm volatile("s_waitcnt vmcnt(4)" ::: "memory");
        else         asm volatile("s_waitcnt vmcnt(0)" ::: "memory");
        __builtin_amdgcn_s_barrier();
        // buffer (kt+2)%3's previous readers (iter kt-1) finished their
        // ds_reads before their MFMAs, which preceded this barrier -> safe.

        const char* bufA = smem + (kt % 3) * 16384;
        const char* bufB = bufA + 8192;

        int32x4 af[4], bf[4];
        #pragma unroll
        for (int i = 0; i < 4; ++i) {
            int row = wm * 64 + i * 16 + (l & 15);
            int ch = (l >> 4) ^ ((row >> 1) & 3);
            af[i] = *(const int32x4*)(bufA + row * 64 + ch * 16);
        }
        #pragma unroll
        for (int i = 0; i < 4; ++i) {
            int row = wn * 64 + i * 16 + (l & 15);
            int ch = (l >> 4) ^ ((row >> 1) & 3);
            bf[i] = *(const int32x4*)(bufB + row * 64 + ch * 16);
        }
        if (kt < 14) stage(kt + 2, (kt + 2) % 3);
        __builtin_amdgcn_s_setprio(1);
        #pragma unroll
        for (int mi = 0; mi < 4; ++mi)
            #pragma unroll
            for (int ni = 0; ni < 4; ++ni)
                acc[mi][ni] = __builtin_amdgcn_mfma_i32_16x16x64_i8(
                    af[mi], bf[ni], acc[mi][ni], 0, 0, 0);
        __builtin_amdgcn_s_setprio(0);
    }

    // epilogue: C/D layout col = lane&15, row = (lane>>4)*4 + reg (verified)
    const float wsc = *wscp, isc = *iscp;
    const int crow = (l >> 4) * 4;
    const int ccol = l & 15;
    #pragma unroll
    for (int mi = 0; mi < 4; ++mi) {
        #pragma unroll
        for (int ni = 0; ni < 4; ++ni) {
            long r0 = m0 + wm * 64 + mi * 16 + crow;
            int c = n0 + wn * 64 + ni * 16 + ccol;
            float b = bias[c];
            #pragma unroll
            for (int j = 0; j < 4; ++j) {
                out[(r0 + j) * MK_N + c] = ((float)acc[mi][ni][j] * wsc) * isc + b;
            }
        }
    }
}

extern "C" void kernel_launch(void* const* d_in, const int* in_sizes, int n_in,
                              void* d_out, int out_size, void* d_ws, size_t ws_size,
                              hipStream_t stream) {
    const float* x = (const float*)d_in[0];
    const float* wt = (const float*)d_in[1];
    const float* bias = (const float*)d_in[2];
    float* out = (float*)d_out;

    if (ws_size < WS_NEEDED) return;

    char* ws = (char*)d_ws;
    float* wscp = (float*)(ws + 0);
    float* iscp = (float*)(ws + 4);
    float* maxp = (float*)(ws + WS_MAXP_OFF);
    double* partials = (double*)(ws + WS_PART_OFF);
    char* qw = ws + WS_QW_OFF;
    char* qx = ws + WS_QX_OFF;

    const long n_x = (long)in_sizes[0];   // 33554432
    const long n4_x = n_x >> 2;

    kprep<<<2112, 256, 0, stream>>>((const float4*)x, (const float4*)wt, maxp, partials, n4_x);
    kquant_w<<<256, 256, 0, stream>>>((const float4*)wt, (unsigned*)qw, partials, wscp);
    kquant_x<<<2048, 256, 0, stream>>>((const float4*)x, (unsigned*)qx, maxp, iscp, n4_x);

    const int grid = (MK_M / 128) * (MK_N / 128);  // 2048
    kgemm<<<grid, 256, 0, stream>>>(qx, qw, bias, wscp, iscp, out);
}